// Round 8
// baseline (1345.050 us; speedup 1.0000x reference)
//
#include <hip/hip_runtime.h>
#include <cstdint>
#include <cstddef>

#define B_ 128
#define T_ 500
#define I_ 512
#define H_ 1024
#define O_ 11
#define BETA 0.9f
#define THRESH 1.0f
#define K2_ 1536  // 3-term split: xh*wh + xl*wh + xh*wl

typedef __attribute__((ext_vector_type(4))) float f32x4;
typedef __attribute__((ext_vector_type(8))) short bf16x8;
typedef __attribute__((ext_vector_type(4))) unsigned int u32x4;

__device__ __forceinline__ unsigned short bf16_rne(float f) {
  unsigned int u = __float_as_uint(f);
  unsigned int r = u + 0x7FFFu + ((u >> 16) & 1u);
  return (unsigned short)(r >> 16);
}
__device__ __forceinline__ float bf16_to_f(unsigned short h) {
  return __uint_as_float(((unsigned int)h) << 16);
}

// ---------------- CSR build: row r = outgoing edges of neuron r, 128 slots -------------------
// entry = (w22 << 10) | target10; pad: w=0, tgt=(slot&63).
__global__ void k_csr(const float* __restrict__ W_rec, const float* __restrict__ mask,
                      unsigned int* __restrict__ csr, unsigned int* __restrict__ rowhi) {
  int r = blockIdx.x * 4 + (threadIdx.x >> 6);  // one wave per row
  int lane = threadIdx.x & 63;
  unsigned cnt = 0;
  const float* mrow = mask + (size_t)r * H_;
  const float* wrow = W_rec + (size_t)r * H_;
  for (int c = 0; c < 16; ++c) {
    float m = mrow[c * 64 + lane];
    bool nz = (m != 0.f);
    unsigned long long bb = __ballot(nz);
    unsigned pos = cnt + (unsigned)__popcll(bb & ((1ull << lane) - 1ull));
    if (nz) {
      float w = wrow[c * 64 + lane] * m;
      int wi = __float2int_rn(w * 8388608.f);  // 2^23
      wi = wi > 2097151 ? 2097151 : (wi < -2097151 ? -2097151 : wi);
      if (pos < 128u) csr[((size_t)r << 7) + pos] = (((unsigned)wi) << 10) | (unsigned)(c * 64 + lane);
    }
    cnt += (unsigned)__popcll(bb);
  }
  for (unsigned p = (cnt > 128u ? 128u : cnt) + (unsigned)lane; p < 128u; p += 64u)
    csr[((size_t)r << 7) + p] = (p & 63u);  // w=0 pad, lane-matched target (conflict-free)
  if (lane == 0) rowhi[r] = (cnt > 64u) ? 1u : 0u;
}

// ---------------- Wt [1024][1536] bf16: k2 = 3*i + c; c: 0->wh, 1->wh, 2->wl ------------------
__global__ void k_build_wt(const float* __restrict__ W_in, unsigned short* __restrict__ Wt) {
  int n = blockIdx.y;
  int k2 = blockIdx.x * 256 + threadIdx.x;  // 0..1535
  int i = k2 / 3;
  int c = k2 - 3 * i;
  float w = W_in[i * H_ + n];
  unsigned short hi = bf16_rne(w);
  unsigned short v = (c == 2) ? bf16_rne(w - bf16_to_f(hi)) : hi;
  Wt[(size_t)n * K2_ + k2] = v;
}

// ---------------- xs chunk [128*Tc][1536] bf16: per f32 j -> {xh, xl, xh} ---------------------
__global__ void k_build_xs(const float* __restrict__ x, unsigned short* __restrict__ xs,
                           int t0, int Tc) {
  int id = blockIdx.x * 256 + threadIdx.x;  // one thread = 8 consecutive f32 -> 24 bf16 (48B)
  int rr = id >> 6;                          // 64 octs per row (512/8)
  int oct = id & 63;
  int b = rr / Tc, tt = rr % Tc;
  const float4 v0 = *(const float4*)&x[((size_t)(b * T_ + t0 + tt)) * I_ + oct * 8];
  const float4 v1 = *(const float4*)&x[((size_t)(b * T_ + t0 + tt)) * I_ + oct * 8 + 4];
  alignas(16) unsigned short o[24];
  float vv[8] = {v0.x, v0.y, v0.z, v0.w, v1.x, v1.y, v1.z, v1.w};
#pragma unroll
  for (int j = 0; j < 8; ++j) {
    unsigned short hi = bf16_rne(vv[j]);
    unsigned short lo = bf16_rne(vv[j] - bf16_to_f(hi));
    o[3 * j + 0] = hi; o[3 * j + 1] = lo; o[3 * j + 2] = hi;
  }
  unsigned short* dst = xs + (size_t)rr * K2_ + oct * 24;
  *(u32x4*)(dst + 0) = *(u32x4*)(o + 0);
  *(u32x4*)(dst + 8) = *(u32x4*)(o + 8);
  *(u32x4*)(dst + 16) = *(u32x4*)(o + 16);
}

// ---------------- split-bf16 GEMM: drive[rr][h], K2=1536 --------------------------------------
#define LDA 72
__global__ __launch_bounds__(512, 1) void k_gemm(const unsigned short* __restrict__ xs,
                                                 const unsigned short* __restrict__ Wt,
                                                 float* __restrict__ drive) {
  __shared__ __align__(16) unsigned short As[128 * LDA];
  __shared__ __align__(16) unsigned short Bs[256 * LDA];
  int mt = blockIdx.x, nt = blockIdx.y;
  int tid = threadIdx.x;
  int lane = tid & 63, w = tid >> 6;
  int wr = w >> 2, wc = w & 3;
  f32x4 acc[4][4] = {};
  int arow = tid >> 2, aq = tid & 3;
  int brow = tid >> 1, bh = tid & 1;
  const unsigned short* xsrow = xs + (size_t)(mt * 128 + arow) * K2_ + aq * 16;
  const unsigned short* wtrow = Wt + (size_t)(nt * 256 + brow) * K2_ + bh * 32;
  for (int kt = 0; kt < K2_ / 64; ++kt) {
    u32x4 a0 = *(const u32x4*)(xsrow + kt * 64);
    u32x4 a1 = *(const u32x4*)(xsrow + kt * 64 + 8);
    u32x4 b0 = *(const u32x4*)(wtrow + kt * 64);
    u32x4 b1 = *(const u32x4*)(wtrow + kt * 64 + 8);
    u32x4 b2 = *(const u32x4*)(wtrow + kt * 64 + 16);
    u32x4 b3 = *(const u32x4*)(wtrow + kt * 64 + 24);
    __syncthreads();
    *(u32x4*)&As[arow * LDA + aq * 16] = a0;
    *(u32x4*)&As[arow * LDA + aq * 16 + 8] = a1;
    *(u32x4*)&Bs[brow * LDA + bh * 32] = b0;
    *(u32x4*)&Bs[brow * LDA + bh * 32 + 8] = b1;
    *(u32x4*)&Bs[brow * LDA + bh * 32 + 16] = b2;
    *(u32x4*)&Bs[brow * LDA + bh * 32 + 24] = b3;
    __syncthreads();
#pragma unroll
    for (int kk = 0; kk < 2; ++kk) {
      bf16x8 af[4], bf[4];
#pragma unroll
      for (int mi = 0; mi < 4; ++mi)
        af[mi] = *(const bf16x8*)&As[(wr * 64 + mi * 16 + (lane & 15)) * LDA + kk * 32 + (lane >> 4) * 8];
#pragma unroll
      for (int ni = 0; ni < 4; ++ni)
        bf[ni] = *(const bf16x8*)&Bs[(wc * 64 + ni * 16 + (lane & 15)) * LDA + kk * 32 + (lane >> 4) * 8];
#pragma unroll
      for (int mi = 0; mi < 4; ++mi)
#pragma unroll
        for (int ni = 0; ni < 4; ++ni)
          acc[mi][ni] = __builtin_amdgcn_mfma_f32_16x16x32_bf16(af[mi], bf[ni], acc[mi][ni], 0, 0, 0);
    }
  }
  int r0 = (lane >> 4) * 4, c0 = lane & 15;
#pragma unroll
  for (int mi = 0; mi < 4; ++mi) {
    int rowb = mt * 128 + wr * 64 + mi * 16 + r0;
#pragma unroll
    for (int ni = 0; ni < 4; ++ni) {
      int col = nt * 256 + wc * 64 + ni * 16 + c0;
#pragma unroll
      for (int r = 0; r < 4; ++r)
        drive[(size_t)(rowb + r) * H_ + col] = acc[mi][ni][r];
    }
  }
}

// ---------------- recurrent scan: listless per-wave scatter, ONE barrier per step -------------
// Each wave owns neurons [wv*64, wv*64+64); fire bits live in the wave's own ballot.
// Scatter indices come from the scalar bitmask (ctz loop), rows loaded before atomics.
#define FDECL(n) int f##n = bb ? (int)__builtin_ctzll(bb) : 64; bb &= bb - 1ull; \
                 unsigned ea##n = 0u, eb##n = 0u; bool hb##n = false;
#define FLOAD(n) if (f##n < 64) { \
        const unsigned int* rp = csr + (((size_t)(wvbase + f##n)) << 7); \
        ea##n = rp[lane]; hb##n = ((hib >> f##n) & 1ull) != 0ull; \
        if (hb##n) eb##n = rp[64 + lane]; }
#define FATOM(n) if (f##n < 64) { \
        atomicAdd(&acc[ea##n & 1023u], ((int)ea##n) >> 10); \
        if (hb##n) atomicAdd(&acc[eb##n & 1023u], ((int)eb##n) >> 10); }

__device__ __forceinline__ void scatter_mine(unsigned long long bb, unsigned long long hib,
                                             int wvbase, int lane,
                                             const unsigned int* __restrict__ csr, int* acc) {
  while (bb) {
    FDECL(0) FDECL(1) FDECL(2) FDECL(3) FDECL(4) FDECL(5) FDECL(6) FDECL(7)
    FLOAD(0) FLOAD(1) FLOAD(2) FLOAD(3) FLOAD(4) FLOAD(5) FLOAD(6) FLOAD(7)
    FATOM(0) FATOM(1) FATOM(2) FATOM(3) FATOM(4) FATOM(5) FATOM(6) FATOM(7)
  }
}

__global__ __launch_bounds__(1024, 1) void k_rsnn(
    const float* __restrict__ drive, const unsigned int* __restrict__ csr,
    const unsigned int* __restrict__ rowhi,
    const float* __restrict__ h_bias, const float* __restrict__ W_out,
    const float* __restrict__ b_out,
    float* __restrict__ state_v, float* __restrict__ state_s, float* __restrict__ state_c,
    float* __restrict__ out, int t0, int Tc, int last) {
  __shared__ int accL[2][H_];
  __shared__ float red[H_];
  __shared__ float part[352];
  int tid = threadIdx.x;
  int b = blockIdx.x;
  int lane = tid & 63;
  int wvbase = tid & ~63;  // wv*64
  float bias = h_bias[tid];
  unsigned long long hib = __ballot(rowhi[tid] != 0u);  // hi-row mask for MY wave's 64 rows
  float v, s, cnt;
  if (t0 == 0) { v = 0.f; s = 0.f; cnt = 0.f; }
  else { v = state_v[b * H_ + tid]; s = state_s[b * H_ + tid]; cnt = state_c[b * H_ + tid]; }
  accL[0][tid] = 0;
  accL[1][tid] = 0;
  __syncthreads();
  {  // scatter carried spikes into acc[0]
    unsigned long long bb = __ballot(s > 0.f);
    scatter_mine(bb, hib, wvbase, lane, csr, accL[0]);
  }
  __syncthreads();
  const float* dptr = drive + (size_t)b * Tc * H_ + tid;
  float dcur = dptr[0];
  for (int t = 0; t < Tc; ++t) {
    float dnxt = (t + 1 < Tc) ? dptr[(size_t)(t + 1) * H_] : 0.f;
    int ri = accL[t & 1][tid];
    accL[t & 1][tid] = 0;
    float rec = (float)ri * 1.1920929e-7f;  // 2^-23
    v = BETA * v + (dcur + bias) + rec;
    bool f = v > THRESH;
    v -= f ? THRESH : 0.f;
    cnt += f ? 1.f : 0.f;
    s = f ? 1.f : 0.f;
    unsigned long long bb = __ballot(f);
    scatter_mine(bb, hib, wvbase, lane, csr, accL[(t + 1) & 1]);
    dcur = dnxt;
    __syncthreads();
  }
  if (!last) {
    state_v[b * H_ + tid] = v; state_s[b * H_ + tid] = s; state_c[b * H_ + tid] = cnt;
  } else {
    red[tid] = cnt;
    __syncthreads();
    if (tid < 352) {
      int o = tid >> 5, seg = tid & 31;
      float p = 0.f;
      for (int j = 0; j < 32; ++j) {
        int hh = seg * 32 + j;
        p += red[hh] * W_out[hh * O_ + o];
      }
      part[tid] = p;
    }
    __syncthreads();
    if (tid < O_) {
      float sum = 0.f;
      for (int g = 0; g < 32; ++g) sum += part[(tid << 5) + g];
      out[b * O_ + tid] = b_out[tid] + sum * (1.0f / (float)T_);
    }
  }
}

extern "C" void kernel_launch(void* const* d_in, const int* in_sizes, int n_in,
                              void* d_out, int out_size, void* d_ws, size_t ws_size,
                              hipStream_t stream) {
  (void)in_sizes; (void)n_in; (void)out_size;
  const float* x = (const float*)d_in[0];
  const float* W_in = (const float*)d_in[1];
  const float* W_rec = (const float*)d_in[2];
  const float* W_out = (const float*)d_in[3];
  const float* h_bias = (const float*)d_in[4];
  const float* b_out = (const float*)d_in[5];
  const float* mask = (const float*)d_in[6];
  float* out = (float*)d_out;

  char* ws = (char*)d_ws;
  size_t off = 0;
  auto alloc = [&](size_t bytes) {
    void* p = ws + off;
    off = (off + bytes + 255) & ~(size_t)255;
    return p;
  };
  unsigned short* Wt = (unsigned short*)alloc((size_t)H_ * K2_ * 2);
  unsigned int* csr = (unsigned int*)alloc((size_t)H_ * 128 * 4);
  unsigned int* rowhi = (unsigned int*)alloc((size_t)H_ * 4);
  float* st_v = (float*)alloc((size_t)B_ * H_ * 4);
  float* st_s = (float*)alloc((size_t)B_ * H_ * 4);
  float* st_c = (float*)alloc((size_t)B_ * H_ * 4);
  size_t fixed = off;

  size_t per_t = (size_t)128 * K2_ * 2 + (size_t)128 * 1024 * 4;
  int Tc = 1;
  if (ws_size > fixed + per_t) Tc = (int)((ws_size - fixed) / per_t);
  if (Tc > T_) Tc = T_;
  if (Tc < 1) Tc = 1;
  unsigned short* xs = (unsigned short*)alloc((size_t)128 * Tc * K2_ * 2);
  float* drive = (float*)alloc((size_t)128 * Tc * 1024 * 4);

  k_csr<<<dim3(256), dim3(256), 0, stream>>>(W_rec, mask, csr, rowhi);
  k_build_wt<<<dim3(6, 1024), dim3(256), 0, stream>>>(W_in, Wt);

  for (int t0 = 0; t0 < T_; t0 += Tc) {
    int tc = (Tc < T_ - t0) ? Tc : (T_ - t0);
    k_build_xs<<<dim3(32 * tc), dim3(256), 0, stream>>>(x, xs, t0, tc);
    k_gemm<<<dim3(tc, 4), dim3(512), 0, stream>>>(xs, Wt, drive);
    k_rsnn<<<dim3(128), dim3(1024), 0, stream>>>(drive, csr, rowhi, h_bias, W_out, b_out,
                                                 st_v, st_s, st_c, out, t0, tc,
                                                 (t0 + tc >= T_) ? 1 : 0);
  }
}